// Round 3
// baseline (298.656 us; speedup 1.0000x reference)
//
#include <hip/hip_runtime.h>

#define NN 50000
#define NE 800000
#define DD 96
#define NEG 0.01f
#define NPI 32      // nodes per fuse block

static __device__ __forceinline__ float lrelu(float x) {
  return (x >= 0.f) ? x : NEG * x;
}
static __device__ __forceinline__ void fma4(float4& a, float v, const float4& x) {
  a.x += v * x.x; a.y += v * x.y; a.z += v * x.z; a.w += v * x.w;
}

// ================= fallback (round-1) path =================
__global__ __launch_bounds__(256) void scatter_kernel(
    const float* __restrict__ ego, const float* __restrict__ avals,
    const int* __restrict__ arows, const int* __restrict__ acols,
    float* __restrict__ side)
{
  int t = blockIdx.x * 256 + threadIdx.x;
  int e = t >> 5;
  int lane = t & 31;
  if (e >= NE) return;
  int row = arows[e];
  int col = acols[e];
  float v = avals[e];
  if (lane < 24) {
    const float4* src = (const float4*)(ego + (size_t)col * DD);
    float4 x = src[lane];
    float* dst = side + (size_t)row * DD + lane * 4;
    unsafeAtomicAdd(dst + 0, v * x.x);
    unsafeAtomicAdd(dst + 1, v * x.y);
    unsafeAtomicAdd(dst + 2, v * x.z);
    unsafeAtomicAdd(dst + 3, v * x.w);
  }
}

__global__ __launch_bounds__(192) void fuse_fb_kernel(
    const float* __restrict__ ego, const float* __restrict__ side,
    const float* __restrict__ W1, const float* __restrict__ b1,
    const float* __restrict__ W2, const float* __restrict__ b2,
    float* __restrict__ out)
{
  __shared__ float W1t[DD * DD];
  __shared__ float W2t[DD * DD];
  __shared__ float b1s[DD], b2s[DD];
  __shared__ float xs[192], ys[192];
  int tid = threadIdx.x;
  for (int i = tid; i < DD * DD; i += 192) {
    int j = i / DD, k = i - j * DD;
    W1t[k * DD + j] = W1[i];
    W2t[k * DD + j] = W2[i];
  }
  if (tid < DD) { b1s[tid] = b1[tid]; b2s[tid] = b2[tid]; }
  __syncthreads();
  int nl = tid / DD, j = tid - nl * DD;
  for (int p = blockIdx.x; p < NN / 2; p += gridDim.x) {
    int base = p * 192;
    float e = ego[base + tid], s = side[base + tid];
    xs[tid] = e + s; ys[tid] = e * s;
    __syncthreads();
    float a1 = b1s[j], a2 = b2s[j];
    const float* xr = xs + nl * DD;
    const float* yr = ys + nl * DD;
#pragma unroll 16
    for (int k = 0; k < DD; ++k) {
      a1 += xr[k] * W1t[k * DD + j];
      a2 += yr[k] * W2t[k * DD + j];
    }
    float r = lrelu(a1) + lrelu(a2);
    __syncthreads();
    out[base + tid] = r;
  }
}

// ================= CSR build =================
// count + W transpose in one dispatch (independent work, saves a launch)
__global__ __launch_bounds__(256) void count_tr_kernel(
    const int* __restrict__ rows, int* __restrict__ cnt,
    const float* __restrict__ W1, const float* __restrict__ W2,
    float* __restrict__ W1t, float* __restrict__ W2t) {
  int b = blockIdx.x;
  if (b < NE / 256) {
    int e = b * 256 + threadIdx.x;
    atomicAdd(&cnt[rows[e]], 1);
  } else {
    int i = (b - NE / 256) * 256 + threadIdx.x;  // DD*DD = 9216 = 36 blocks
    int j = i / DD, k = i - j * DD;
    W1t[k * DD + j] = W1[i];
    W2t[k * DD + j] = W2[i];
  }
}

// single-block exclusive scan over NN counters (replaces 3 kernels)
#define SCAN_T 1024
#define CHUNK 49   // 1024*49 = 50176 >= NN+1
__global__ __launch_bounds__(1024) void scan_kernel(
    const int* __restrict__ cnt, int* __restrict__ row_start,
    int* __restrict__ wptr) {
  __shared__ int part[SCAN_T];
  int t = threadIdx.x;
  int base = t * CHUNK;
  int sum = 0;
#pragma unroll
  for (int i = 0; i < CHUNK; ++i) {
    int idx = base + i;
    if (idx < NN) sum += cnt[idx];
  }
  part[t] = sum;
  __syncthreads();
  for (int off = 1; off < SCAN_T; off <<= 1) {
    int v = (t >= off) ? part[t - off] : 0;
    __syncthreads();
    part[t] += v;
    __syncthreads();
  }
  int run = part[t] - sum;  // exclusive prefix
  for (int i = 0; i < CHUNK; ++i) {
    int idx = base + i;
    if (idx < NN) {
      row_start[idx] = run;
      wptr[idx] = run;
      run += cnt[idx];
    } else if (idx == NN) {
      row_start[NN] = NE;
    }
  }
}

__global__ __launch_bounds__(256) void fill_kernel(
    const int* __restrict__ rows, const int* __restrict__ cols,
    const float* __restrict__ vals, int* __restrict__ wptr,
    int2* __restrict__ cv) {
  int e = blockIdx.x * 256 + threadIdx.x;  // grid exactly NE/256
  int r = rows[e];
  int p = atomicAdd(&wptr[r], 1);
  cv[p] = make_int2(cols[e], __float_as_int(vals[e]));
}

// ============ segment reduction: wave/row, 8 edges in flight ============
__global__ __launch_bounds__(256) void agg_kernel(
    const float* __restrict__ ego, const int* __restrict__ row_start,
    const int2* __restrict__ cv, float* __restrict__ side) {
  int wid = threadIdx.x >> 6, lane = threadIdx.x & 63;
  int row = blockIdx.x * 4 + wid;
  if (row >= NN) return;
  int s = row_start[row], e = row_start[row + 1];
  int half = lane >> 5, hl = lane & 31;
  float4 a0 = {0, 0, 0, 0}, a1 = a0, a2 = a0, a3 = a0;

  for (int base = s; base < e; base += 64) {
    int idx = base + lane;
    int cc = 0; float vv = 0.f;
    if (idx < e) {
      int2 p = cv[idx];
      cc = p.x;
      vv = __int_as_float(p.y);
    }
    int n = min(64, e - base);
    // 8 edges/iter: half0 -> even slots, half1 -> odd slots, 4-deep per half
    for (int i = 0; i < n; i += 8) {
      int c0 = __shfl(cc, i + half, 64);     float v0 = __shfl(vv, i + half, 64);
      int c1 = __shfl(cc, i + 2 + half, 64); float v1 = __shfl(vv, i + 2 + half, 64);
      int c2 = __shfl(cc, i + 4 + half, 64); float v2 = __shfl(vv, i + 4 + half, 64);
      int c3 = __shfl(cc, i + 6 + half, 64); float v3 = __shfl(vv, i + 6 + half, 64);
      if (hl < 24) {
        float4 x0 = *((const float4*)(ego + (size_t)c0 * DD) + hl);
        float4 x1 = *((const float4*)(ego + (size_t)c1 * DD) + hl);
        float4 x2 = *((const float4*)(ego + (size_t)c2 * DD) + hl);
        float4 x3 = *((const float4*)(ego + (size_t)c3 * DD) + hl);
        fma4(a0, v0, x0);
        fma4(a1, v1, x1);
        fma4(a2, v2, x2);
        fma4(a3, v3, x3);
      }
    }
  }
  float4 acc;
  acc.x = (a0.x + a1.x) + (a2.x + a3.x);
  acc.y = (a0.y + a1.y) + (a2.y + a3.y);
  acc.z = (a0.z + a1.z) + (a2.z + a3.z);
  acc.w = (a0.w + a1.w) + (a2.w + a3.w);
  // fold half1 into half0 (butterfly; both halves end with the sum)
  acc.x += __shfl(acc.x, lane ^ 32, 64);
  acc.y += __shfl(acc.y, lane ^ 32, 64);
  acc.z += __shfl(acc.z, lane ^ 32, 64);
  acc.w += __shfl(acc.w, lane ^ 32, 64);
  if (half == 0 && hl < 24)
    *((float4*)(side + (size_t)row * DD) + hl) = acc;
}

// ========== fused bi-interaction, b128 LDS reads, k-step 4 ==========
__global__ __launch_bounds__(192) void fuse3_kernel(
    const float* __restrict__ ego, const float* __restrict__ side,
    const float* __restrict__ W1t, const float* __restrict__ W2t,
    const float* __restrict__ b1, const float* __restrict__ b2,
    float* __restrict__ out)
{
  __shared__ float xs[NPI][100];  // stride 100: 16B-aligned rows, bank-spread
  __shared__ float ys[NPI][100];
  int tid = threadIdx.x;
  int nbase = blockIdx.x * NPI;
  size_t gbase = (size_t)nbase * DD;

  for (int i = tid; i < NPI * DD; i += 192) {
    int n = i / DD, k = i - n * DD;
    float e = 0.f, s = 0.f;
    if (nbase + n < NN) {
      e = ego[gbase + i];
      s = side[gbase + i];
    }
    xs[n][k] = e + s;
    ys[n][k] = e * s;
  }
  __syncthreads();

  int ng = tid / 24;        // 0..7 -> 4 nodes each
  int jt = tid - ng * 24;   // 0..23 -> 4 j-columns each
  int j0 = jt * 4;
  int n0 = ng * 4;

  float4 bb1 = *(const float4*)(b1 + j0);
  float4 bb2 = *(const float4*)(b2 + j0);
  float4 acc1[4], acc2[4];
#pragma unroll
  for (int ni = 0; ni < 4; ++ni) { acc1[ni] = bb1; acc2[ni] = bb2; }

  for (int k = 0; k < DD; k += 4) {
    float4 w1[4], w2[4];
#pragma unroll
    for (int kk = 0; kk < 4; ++kk) {
      w1[kk] = *(const float4*)(W1t + (k + kk) * DD + j0);
      w2[kk] = *(const float4*)(W2t + (k + kk) * DD + j0);
    }
#pragma unroll
    for (int ni = 0; ni < 4; ++ni) {
      float4 xq = *(const float4*)&xs[n0 + ni][k];
      float4 yq = *(const float4*)&ys[n0 + ni][k];
      fma4(acc1[ni], xq.x, w1[0]); fma4(acc1[ni], xq.y, w1[1]);
      fma4(acc1[ni], xq.z, w1[2]); fma4(acc1[ni], xq.w, w1[3]);
      fma4(acc2[ni], yq.x, w2[0]); fma4(acc2[ni], yq.y, w2[1]);
      fma4(acc2[ni], yq.z, w2[2]); fma4(acc2[ni], yq.w, w2[3]);
    }
  }

#pragma unroll
  for (int ni = 0; ni < 4; ++ni) {
    int n = nbase + n0 + ni;
    if (n < NN) {
      float4 r;
      r.x = lrelu(acc1[ni].x) + lrelu(acc2[ni].x);
      r.y = lrelu(acc1[ni].y) + lrelu(acc2[ni].y);
      r.z = lrelu(acc1[ni].z) + lrelu(acc2[ni].z);
      r.w = lrelu(acc1[ni].w) + lrelu(acc2[ni].w);
      *((float4*)(out + (size_t)n * DD) + jt) = r;
    }
  }
}

// ================= launch =================
extern "C" void kernel_launch(void* const* d_in, const int* in_sizes, int n_in,
                              void* d_out, int out_size, void* d_ws, size_t ws_size,
                              hipStream_t stream) {
  const float* ego   = (const float*)d_in[0];
  const float* avals = (const float*)d_in[1];
  const float* W1    = (const float*)d_in[2];
  const float* b1    = (const float*)d_in[3];
  const float* W2    = (const float*)d_in[4];
  const float* b2    = (const float*)d_in[5];
  const int* arows   = (const int*)d_in[6];
  const int* acols   = (const int*)d_in[7];
  float* out = (float*)d_out;

  size_t off = 0;
  auto bump = [&](size_t bytes) {
    size_t o = off;
    off += (bytes + 1023) & ~(size_t)1023;
    return o;
  };
  char* ws = (char*)d_ws;
  size_t o_cnt  = bump((size_t)NN * 4);
  size_t o_rs   = bump((size_t)(NN + 1) * 4);
  size_t o_wp   = bump((size_t)NN * 4);
  size_t o_cv   = bump((size_t)NE * 8);
  size_t o_w1t  = bump((size_t)DD * DD * 4);
  size_t o_w2t  = bump((size_t)DD * DD * 4);
  size_t o_side = bump((size_t)NN * DD * 4);
  size_t need = off;

  if (ws_size >= need) {
    int*   cnt  = (int*)(ws + o_cnt);
    int*   rs   = (int*)(ws + o_rs);
    int*   wp   = (int*)(ws + o_wp);
    int2*  cv   = (int2*)(ws + o_cv);
    float* W1t  = (float*)(ws + o_w1t);
    float* W2t  = (float*)(ws + o_w2t);
    float* side = (float*)(ws + o_side);

    hipMemsetAsync(cnt, 0, (size_t)NN * 4, stream);
    count_tr_kernel<<<NE / 256 + (DD * DD) / 256, 256, 0, stream>>>(
        arows, cnt, W1, W2, W1t, W2t);
    scan_kernel<<<1, SCAN_T, 0, stream>>>(cnt, rs, wp);
    fill_kernel<<<NE / 256, 256, 0, stream>>>(arows, acols, avals, wp, cv);
    agg_kernel<<<(NN + 3) / 4, 256, 0, stream>>>(ego, rs, cv, side);
    fuse3_kernel<<<(NN + NPI - 1) / NPI, 192, 0, stream>>>(
        ego, side, W1t, W2t, b1, b2, out);
  } else {
    size_t side_bytes = (size_t)NN * DD * sizeof(float);
    float* side = (ws_size >= side_bytes) ? (float*)d_ws : out;
    hipMemsetAsync(side, 0, side_bytes, stream);
    long long nthreads = (long long)NE * 32;
    int blocks = (int)((nthreads + 255) / 256);
    scatter_kernel<<<blocks, 256, 0, stream>>>(ego, avals, arows, acols, side);
    fuse_fb_kernel<<<1024, 192, 0, stream>>>(ego, side, W1, b1, W2, b2, out);
  }
}

// Round 4
// 187.831 us; speedup vs baseline: 1.5900x; 1.5900x over previous
//
#include <hip/hip_runtime.h>

#define NN 50000
#define NE 800000
#define DD 96
#define NEG 0.01f
#define NB 196      // scan blocks: 196*256 = 50176 >= NN
#define NPI 32      // nodes per fuse block

static __device__ __forceinline__ float lrelu(float x) {
  return (x >= 0.f) ? x : NEG * x;
}
static __device__ __forceinline__ void fma4(float4& a, float v, const float4& x) {
  a.x += v * x.x; a.y += v * x.y; a.z += v * x.z; a.w += v * x.w;
}

// ================= fallback (round-1) path =================
__global__ __launch_bounds__(256) void scatter_kernel(
    const float* __restrict__ ego, const float* __restrict__ avals,
    const int* __restrict__ arows, const int* __restrict__ acols,
    float* __restrict__ side)
{
  int t = blockIdx.x * 256 + threadIdx.x;
  int e = t >> 5;
  int lane = t & 31;
  if (e >= NE) return;
  int row = arows[e];
  int col = acols[e];
  float v = avals[e];
  if (lane < 24) {
    const float4* src = (const float4*)(ego + (size_t)col * DD);
    float4 x = src[lane];
    float* dst = side + (size_t)row * DD + lane * 4;
    unsafeAtomicAdd(dst + 0, v * x.x);
    unsafeAtomicAdd(dst + 1, v * x.y);
    unsafeAtomicAdd(dst + 2, v * x.z);
    unsafeAtomicAdd(dst + 3, v * x.w);
  }
}

__global__ __launch_bounds__(192) void fuse_fb_kernel(
    const float* __restrict__ ego, const float* __restrict__ side,
    const float* __restrict__ W1, const float* __restrict__ b1,
    const float* __restrict__ W2, const float* __restrict__ b2,
    float* __restrict__ out)
{
  __shared__ float W1t[DD * DD];
  __shared__ float W2t[DD * DD];
  __shared__ float b1s[DD], b2s[DD];
  __shared__ float xs[192], ys[192];
  int tid = threadIdx.x;
  for (int i = tid; i < DD * DD; i += 192) {
    int j = i / DD, k = i - j * DD;
    W1t[k * DD + j] = W1[i];
    W2t[k * DD + j] = W2[i];
  }
  if (tid < DD) { b1s[tid] = b1[tid]; b2s[tid] = b2[tid]; }
  __syncthreads();
  int nl = tid / DD, j = tid - nl * DD;
  for (int p = blockIdx.x; p < NN / 2; p += gridDim.x) {
    int base = p * 192;
    float e = ego[base + tid], s = side[base + tid];
    xs[tid] = e + s; ys[tid] = e * s;
    __syncthreads();
    float a1 = b1s[j], a2 = b2s[j];
    const float* xr = xs + nl * DD;
    const float* yr = ys + nl * DD;
#pragma unroll 16
    for (int k = 0; k < DD; ++k) {
      a1 += xr[k] * W1t[k * DD + j];
      a2 += yr[k] * W2t[k * DD + j];
    }
    float r = lrelu(a1) + lrelu(a2);
    __syncthreads();
    out[base + tid] = r;
  }
}

// ================= CSR build =================
// count + W transpose in one dispatch (independent work, saves a launch)
__global__ __launch_bounds__(256) void count_tr_kernel(
    const int* __restrict__ rows, int* __restrict__ cnt,
    const float* __restrict__ W1, const float* __restrict__ W2,
    float* __restrict__ W1t, float* __restrict__ W2t) {
  int b = blockIdx.x;
  if (b < NE / 256) {
    int e = b * 256 + threadIdx.x;
    atomicAdd(&cnt[rows[e]], 1);
  } else {
    int i = (b - NE / 256) * 256 + threadIdx.x;  // DD*DD = 9216 = 36 blocks
    int j = i / DD, k = i - j * DD;
    W1t[k * DD + j] = W1[i];
    W2t[k * DD + j] = W2[i];
  }
}

// 3-kernel parallel exclusive scan (R2-proven, ~few us each)
__global__ __launch_bounds__(256) void scan1_kernel(const int* __restrict__ cnt,
                                                    int* __restrict__ bsum) {
  __shared__ int s[256];
  int t = threadIdx.x, i = blockIdx.x * 256 + t;
  s[t] = (i < NN) ? cnt[i] : 0;
  __syncthreads();
  for (int off = 128; off > 0; off >>= 1) {
    if (t < off) s[t] += s[t + off];
    __syncthreads();
  }
  if (t == 0) bsum[blockIdx.x] = s[0];
}

__global__ __launch_bounds__(256) void scan2_kernel(const int* __restrict__ bsum,
                                                    int* __restrict__ bexcl) {
  __shared__ int s[256];
  int t = threadIdx.x;
  int v = (t < NB) ? bsum[t] : 0;
  s[t] = v;
  __syncthreads();
  for (int off = 1; off < 256; off <<= 1) {
    int add = (t >= off) ? s[t - off] : 0;
    __syncthreads();
    s[t] += add;
    __syncthreads();
  }
  if (t < NB) bexcl[t] = s[t] - v;
}

__global__ __launch_bounds__(256) void scan3_kernel(const int* __restrict__ cnt,
                                                    const int* __restrict__ bexcl,
                                                    int* __restrict__ row_start,
                                                    int* __restrict__ wptr) {
  __shared__ int s[256];
  int t = threadIdx.x, i = blockIdx.x * 256 + t;
  int v = (i < NN) ? cnt[i] : 0;
  s[t] = v;
  __syncthreads();
  for (int off = 1; off < 256; off <<= 1) {
    int add = (t >= off) ? s[t - off] : 0;
    __syncthreads();
    s[t] += add;
    __syncthreads();
  }
  int rs = bexcl[blockIdx.x] + s[t] - v;
  if (i < NN) { row_start[i] = rs; wptr[i] = rs; }
  if (i == NN) row_start[NN] = NE;
}

__global__ __launch_bounds__(256) void fill_kernel(
    const int* __restrict__ rows, const int* __restrict__ cols,
    const float* __restrict__ vals, int* __restrict__ wptr,
    int2* __restrict__ cv) {
  int e = blockIdx.x * 256 + threadIdx.x;  // grid exactly NE/256
  int r = rows[e];
  int p = atomicAdd(&wptr[r], 1);
  cv[p] = make_int2(cols[e], __float_as_int(vals[e]));
}

// ============ segment reduction: wave/row, 8 edges in flight ============
__global__ __launch_bounds__(256) void agg_kernel(
    const float* __restrict__ ego, const int* __restrict__ row_start,
    const int2* __restrict__ cv, float* __restrict__ side) {
  int wid = threadIdx.x >> 6, lane = threadIdx.x & 63;
  int row = blockIdx.x * 4 + wid;
  if (row >= NN) return;
  int s = row_start[row], e = row_start[row + 1];
  int half = lane >> 5, hl = lane & 31;
  float4 a0 = {0, 0, 0, 0}, a1 = a0, a2 = a0, a3 = a0;

  for (int base = s; base < e; base += 64) {
    int idx = base + lane;
    int cc = 0; float vv = 0.f;
    if (idx < e) {
      int2 p = cv[idx];
      cc = p.x;
      vv = __int_as_float(p.y);
    }
    int n = min(64, e - base);
    for (int i = 0; i < n; i += 8) {
      int c0 = __shfl(cc, i + half, 64);     float v0 = __shfl(vv, i + half, 64);
      int c1 = __shfl(cc, i + 2 + half, 64); float v1 = __shfl(vv, i + 2 + half, 64);
      int c2 = __shfl(cc, i + 4 + half, 64); float v2 = __shfl(vv, i + 4 + half, 64);
      int c3 = __shfl(cc, i + 6 + half, 64); float v3 = __shfl(vv, i + 6 + half, 64);
      if (hl < 24) {
        float4 x0 = *((const float4*)(ego + (size_t)c0 * DD) + hl);
        float4 x1 = *((const float4*)(ego + (size_t)c1 * DD) + hl);
        float4 x2 = *((const float4*)(ego + (size_t)c2 * DD) + hl);
        float4 x3 = *((const float4*)(ego + (size_t)c3 * DD) + hl);
        fma4(a0, v0, x0);
        fma4(a1, v1, x1);
        fma4(a2, v2, x2);
        fma4(a3, v3, x3);
      }
    }
  }
  float4 acc;
  acc.x = (a0.x + a1.x) + (a2.x + a3.x);
  acc.y = (a0.y + a1.y) + (a2.y + a3.y);
  acc.z = (a0.z + a1.z) + (a2.z + a3.z);
  acc.w = (a0.w + a1.w) + (a2.w + a3.w);
  acc.x += __shfl(acc.x, lane ^ 32, 64);
  acc.y += __shfl(acc.y, lane ^ 32, 64);
  acc.z += __shfl(acc.z, lane ^ 32, 64);
  acc.w += __shfl(acc.w, lane ^ 32, 64);
  if (half == 0 && hl < 24)
    *((float4*)(side + (size_t)row * DD) + hl) = acc;
}

// ========== fused bi-interaction, b128 LDS reads, k-step 4 ==========
__global__ __launch_bounds__(192) void fuse3_kernel(
    const float* __restrict__ ego, const float* __restrict__ side,
    const float* __restrict__ W1t, const float* __restrict__ W2t,
    const float* __restrict__ b1, const float* __restrict__ b2,
    float* __restrict__ out)
{
  __shared__ float xs[NPI][100];
  __shared__ float ys[NPI][100];
  int tid = threadIdx.x;
  int nbase = blockIdx.x * NPI;
  size_t gbase = (size_t)nbase * DD;

  for (int i = tid; i < NPI * DD; i += 192) {
    int n = i / DD, k = i - n * DD;
    float e = 0.f, s = 0.f;
    if (nbase + n < NN) {
      e = ego[gbase + i];
      s = side[gbase + i];
    }
    xs[n][k] = e + s;
    ys[n][k] = e * s;
  }
  __syncthreads();

  int ng = tid / 24;
  int jt = tid - ng * 24;
  int j0 = jt * 4;
  int n0 = ng * 4;

  float4 bb1 = *(const float4*)(b1 + j0);
  float4 bb2 = *(const float4*)(b2 + j0);
  float4 acc1[4], acc2[4];
#pragma unroll
  for (int ni = 0; ni < 4; ++ni) { acc1[ni] = bb1; acc2[ni] = bb2; }

  for (int k = 0; k < DD; k += 4) {
    float4 w1[4], w2[4];
#pragma unroll
    for (int kk = 0; kk < 4; ++kk) {
      w1[kk] = *(const float4*)(W1t + (k + kk) * DD + j0);
      w2[kk] = *(const float4*)(W2t + (k + kk) * DD + j0);
    }
#pragma unroll
    for (int ni = 0; ni < 4; ++ni) {
      float4 xq = *(const float4*)&xs[n0 + ni][k];
      float4 yq = *(const float4*)&ys[n0 + ni][k];
      fma4(acc1[ni], xq.x, w1[0]); fma4(acc1[ni], xq.y, w1[1]);
      fma4(acc1[ni], xq.z, w1[2]); fma4(acc1[ni], xq.w, w1[3]);
      fma4(acc2[ni], yq.x, w2[0]); fma4(acc2[ni], yq.y, w2[1]);
      fma4(acc2[ni], yq.z, w2[2]); fma4(acc2[ni], yq.w, w2[3]);
    }
  }

#pragma unroll
  for (int ni = 0; ni < 4; ++ni) {
    int n = nbase + n0 + ni;
    if (n < NN) {
      float4 r;
      r.x = lrelu(acc1[ni].x) + lrelu(acc2[ni].x);
      r.y = lrelu(acc1[ni].y) + lrelu(acc2[ni].y);
      r.z = lrelu(acc1[ni].z) + lrelu(acc2[ni].z);
      r.w = lrelu(acc1[ni].w) + lrelu(acc2[ni].w);
      *((float4*)(out + (size_t)n * DD) + jt) = r;
    }
  }
}

// ================= launch =================
extern "C" void kernel_launch(void* const* d_in, const int* in_sizes, int n_in,
                              void* d_out, int out_size, void* d_ws, size_t ws_size,
                              hipStream_t stream) {
  const float* ego   = (const float*)d_in[0];
  const float* avals = (const float*)d_in[1];
  const float* W1    = (const float*)d_in[2];
  const float* b1    = (const float*)d_in[3];
  const float* W2    = (const float*)d_in[4];
  const float* b2    = (const float*)d_in[5];
  const int* arows   = (const int*)d_in[6];
  const int* acols   = (const int*)d_in[7];
  float* out = (float*)d_out;

  size_t off = 0;
  auto bump = [&](size_t bytes) {
    size_t o = off;
    off += (bytes + 1023) & ~(size_t)1023;
    return o;
  };
  char* ws = (char*)d_ws;
  size_t o_cnt  = bump((size_t)NN * 4);
  size_t o_rs   = bump((size_t)(NN + 1) * 4);
  size_t o_wp   = bump((size_t)NN * 4);
  size_t o_bs   = bump((size_t)NB * 4);
  size_t o_be   = bump((size_t)NB * 4);
  size_t o_cv   = bump((size_t)NE * 8);
  size_t o_w1t  = bump((size_t)DD * DD * 4);
  size_t o_w2t  = bump((size_t)DD * DD * 4);
  size_t o_side = bump((size_t)NN * DD * 4);
  size_t need = off;

  if (ws_size >= need) {
    int*   cnt  = (int*)(ws + o_cnt);
    int*   rs   = (int*)(ws + o_rs);
    int*   wp   = (int*)(ws + o_wp);
    int*   bs   = (int*)(ws + o_bs);
    int*   be   = (int*)(ws + o_be);
    int2*  cv   = (int2*)(ws + o_cv);
    float* W1t  = (float*)(ws + o_w1t);
    float* W2t  = (float*)(ws + o_w2t);
    float* side = (float*)(ws + o_side);

    hipMemsetAsync(cnt, 0, (size_t)NN * 4, stream);
    count_tr_kernel<<<NE / 256 + (DD * DD) / 256, 256, 0, stream>>>(
        arows, cnt, W1, W2, W1t, W2t);
    scan1_kernel<<<NB, 256, 0, stream>>>(cnt, bs);
    scan2_kernel<<<1, 256, 0, stream>>>(bs, be);
    scan3_kernel<<<NB, 256, 0, stream>>>(cnt, be, rs, wp);
    fill_kernel<<<NE / 256, 256, 0, stream>>>(arows, acols, avals, wp, cv);
    agg_kernel<<<(NN + 3) / 4, 256, 0, stream>>>(ego, rs, cv, side);
    fuse3_kernel<<<(NN + NPI - 1) / NPI, 192, 0, stream>>>(
        ego, side, W1t, W2t, b1, b2, out);
  } else {
    size_t side_bytes = (size_t)NN * DD * sizeof(float);
    float* side = (ws_size >= side_bytes) ? (float*)d_ws : out;
    hipMemsetAsync(side, 0, side_bytes, stream);
    long long nthreads = (long long)NE * 32;
    int blocks = (int)((nthreads + 255) / 256);
    scatter_kernel<<<blocks, 256, 0, stream>>>(ego, avals, arows, acols, side);
    fuse_fb_kernel<<<1024, 192, 0, stream>>>(ego, side, W1, b1, W2, b2, out);
  }
}

// Round 5
// 165.530 us; speedup vs baseline: 1.8042x; 1.1347x over previous
//
#include <hip/hip_runtime.h>

#define NN 50000
#define NE 800000
#define DD 96
#define NEG 0.01f
#define NB 196      // scan blocks: 196*256 = 50176 >= NN
#define FN 64       // nodes per fuse4 block
#define XST 104     // LDS row stride (bf16 units): 208 B, 16B-aligned

typedef __attribute__((ext_vector_type(8))) short short8v;
typedef __attribute__((ext_vector_type(4))) short short4v;
typedef __attribute__((ext_vector_type(4))) float f32x4;

static __device__ __forceinline__ float lrelu(float x) {
  return (x >= 0.f) ? x : NEG * x;
}
static __device__ __forceinline__ void fma4(float4& a, float v, const float4& x) {
  a.x += v * x.x; a.y += v * x.y; a.z += v * x.z; a.w += v * x.w;
}
static __device__ __forceinline__ unsigned short f2bf(float x) {
  unsigned u = __float_as_uint(x);
  u += 0x7fffu + ((u >> 16) & 1u);   // RNE
  return (unsigned short)(u >> 16);
}
static __device__ __forceinline__ float bf2f(unsigned short h) {
  return __uint_as_float(((unsigned)h) << 16);
}

// ================= fallback (round-1) path =================
__global__ __launch_bounds__(256) void scatter_kernel(
    const float* __restrict__ ego, const float* __restrict__ avals,
    const int* __restrict__ arows, const int* __restrict__ acols,
    float* __restrict__ side)
{
  int t = blockIdx.x * 256 + threadIdx.x;
  int e = t >> 5;
  int lane = t & 31;
  if (e >= NE) return;
  int row = arows[e];
  int col = acols[e];
  float v = avals[e];
  if (lane < 24) {
    const float4* src = (const float4*)(ego + (size_t)col * DD);
    float4 x = src[lane];
    float* dst = side + (size_t)row * DD + lane * 4;
    unsafeAtomicAdd(dst + 0, v * x.x);
    unsafeAtomicAdd(dst + 1, v * x.y);
    unsafeAtomicAdd(dst + 2, v * x.z);
    unsafeAtomicAdd(dst + 3, v * x.w);
  }
}

__global__ __launch_bounds__(192) void fuse_fb_kernel(
    const float* __restrict__ ego, const float* __restrict__ side,
    const float* __restrict__ W1, const float* __restrict__ b1,
    const float* __restrict__ W2, const float* __restrict__ b2,
    float* __restrict__ out)
{
  __shared__ float W1t[DD * DD];
  __shared__ float W2t[DD * DD];
  __shared__ float b1s[DD], b2s[DD];
  __shared__ float xs[192], ys[192];
  int tid = threadIdx.x;
  for (int i = tid; i < DD * DD; i += 192) {
    int j = i / DD, k = i - j * DD;
    W1t[k * DD + j] = W1[i];
    W2t[k * DD + j] = W2[i];
  }
  if (tid < DD) { b1s[tid] = b1[tid]; b2s[tid] = b2[tid]; }
  __syncthreads();
  int nl = tid / DD, j = tid - nl * DD;
  for (int p = blockIdx.x; p < NN / 2; p += gridDim.x) {
    int base = p * 192;
    float e = ego[base + tid], s = side[base + tid];
    xs[tid] = e + s; ys[tid] = e * s;
    __syncthreads();
    float a1 = b1s[j], a2 = b2s[j];
    const float* xr = xs + nl * DD;
    const float* yr = ys + nl * DD;
#pragma unroll 16
    for (int k = 0; k < DD; ++k) {
      a1 += xr[k] * W1t[k * DD + j];
      a2 += yr[k] * W2t[k * DD + j];
    }
    float r = lrelu(a1) + lrelu(a2);
    __syncthreads();
    out[base + tid] = r;
  }
}

// ========== prep: edge count + W->bf16 + ego->bf16 (one dispatch) ==========
#define NB_CNT (NE / 256)          // 3125
#define NB_W   ((DD * DD) / 256)   // 36
#define NE4    (NN * DD / 4)       // 1200000 float4 units
#define NB_E   ((NE4 + 255) / 256) // 4688
__global__ __launch_bounds__(256) void prep_kernel(
    const int* __restrict__ rows, int* __restrict__ cnt,
    const float* __restrict__ W1, const float* __restrict__ W2,
    unsigned short* __restrict__ Wb1, unsigned short* __restrict__ Wb2,
    const float* __restrict__ ego, unsigned short* __restrict__ egob)
{
  int b = blockIdx.x;
  if (b < NB_CNT) {
    atomicAdd(&cnt[rows[b * 256 + threadIdx.x]], 1);
  } else if (b < NB_CNT + NB_W) {
    int i = (b - NB_CNT) * 256 + threadIdx.x;  // [0, 9216)
    Wb1[i] = f2bf(W1[i]);
    Wb2[i] = f2bf(W2[i]);
  } else {
    int i = (b - NB_CNT - NB_W) * 256 + threadIdx.x;
    if (i < NE4) {
      float4 v = ((const float4*)ego)[i];
      short4v o;
      o.x = (short)f2bf(v.x); o.y = (short)f2bf(v.y);
      o.z = (short)f2bf(v.z); o.w = (short)f2bf(v.w);
      ((short4v*)egob)[i] = o;
    }
  }
}

// ================= 3-kernel parallel exclusive scan =================
__global__ __launch_bounds__(256) void scan1_kernel(const int* __restrict__ cnt,
                                                    int* __restrict__ bsum) {
  __shared__ int s[256];
  int t = threadIdx.x, i = blockIdx.x * 256 + t;
  s[t] = (i < NN) ? cnt[i] : 0;
  __syncthreads();
  for (int off = 128; off > 0; off >>= 1) {
    if (t < off) s[t] += s[t + off];
    __syncthreads();
  }
  if (t == 0) bsum[blockIdx.x] = s[0];
}

__global__ __launch_bounds__(256) void scan2_kernel(const int* __restrict__ bsum,
                                                    int* __restrict__ bexcl) {
  __shared__ int s[256];
  int t = threadIdx.x;
  int v = (t < NB) ? bsum[t] : 0;
  s[t] = v;
  __syncthreads();
  for (int off = 1; off < 256; off <<= 1) {
    int add = (t >= off) ? s[t - off] : 0;
    __syncthreads();
    s[t] += add;
    __syncthreads();
  }
  if (t < NB) bexcl[t] = s[t] - v;
}

__global__ __launch_bounds__(256) void scan3_kernel(const int* __restrict__ cnt,
                                                    const int* __restrict__ bexcl,
                                                    int* __restrict__ row_start,
                                                    int* __restrict__ wptr) {
  __shared__ int s[256];
  int t = threadIdx.x, i = blockIdx.x * 256 + t;
  int v = (i < NN) ? cnt[i] : 0;
  s[t] = v;
  __syncthreads();
  for (int off = 1; off < 256; off <<= 1) {
    int add = (t >= off) ? s[t - off] : 0;
    __syncthreads();
    s[t] += add;
    __syncthreads();
  }
  int rs = bexcl[blockIdx.x] + s[t] - v;
  if (i < NN) { row_start[i] = rs; wptr[i] = rs; }
  if (i == NN) row_start[NN] = NE;
}

__global__ __launch_bounds__(256) void fill_kernel(
    const int* __restrict__ rows, const int* __restrict__ cols,
    const float* __restrict__ vals, int* __restrict__ wptr,
    int2* __restrict__ cv) {
  int e = blockIdx.x * 256 + threadIdx.x;  // grid exactly NE/256
  int r = rows[e];
  int p = atomicAdd(&wptr[r], 1);
  cv[p] = make_int2(cols[e], __float_as_int(vals[e]));
}

// ====== segment reduction: wave/row, bf16 gathers, 16 edges in flight ======
__global__ __launch_bounds__(256) void agg_kernel(
    const unsigned short* __restrict__ egob, const int* __restrict__ row_start,
    const int2* __restrict__ cv, float* __restrict__ side) {
  int wid = threadIdx.x >> 6, lane = threadIdx.x & 63;
  int row = blockIdx.x * 4 + wid;
  if (row >= NN) return;
  int s = row_start[row], e = row_start[row + 1];
  int half = lane >> 5, hl = lane & 31;
  float4 a[8];
#pragma unroll
  for (int d = 0; d < 8; ++d) a[d] = make_float4(0.f, 0.f, 0.f, 0.f);

  for (int base = s; base < e; base += 64) {
    int idx = base + lane;
    int cc = 0; float vv = 0.f;
    if (idx < e) {
      int2 p = cv[idx];
      cc = p.x;
      vv = __int_as_float(p.y);
    }
    int n = min(64, e - base);
    // 16 edges/iter: half h takes slots i + 2d + h; invalid slots have vv=0
    // (their cc=0 loads hit the L1-hot row 0, contribute 0)
    for (int i = 0; i < n; i += 16) {
#pragma unroll
      for (int d = 0; d < 8; ++d) {
        int c = __shfl(cc, i + 2 * d + half, 64);
        float v = __shfl(vv, i + 2 * d + half, 64);
        if (hl < 24) {
          short4v x = ((const short4v*)(egob + (size_t)c * DD))[hl];
          float4 xf = make_float4(bf2f((unsigned short)x.x),
                                  bf2f((unsigned short)x.y),
                                  bf2f((unsigned short)x.z),
                                  bf2f((unsigned short)x.w));
          fma4(a[d], v, xf);
        }
      }
    }
  }
  float4 acc;
  acc.x = ((a[0].x + a[1].x) + (a[2].x + a[3].x)) + ((a[4].x + a[5].x) + (a[6].x + a[7].x));
  acc.y = ((a[0].y + a[1].y) + (a[2].y + a[3].y)) + ((a[4].y + a[5].y) + (a[6].y + a[7].y));
  acc.z = ((a[0].z + a[1].z) + (a[2].z + a[3].z)) + ((a[4].z + a[5].z) + (a[6].z + a[7].z));
  acc.w = ((a[0].w + a[1].w) + (a[2].w + a[3].w)) + ((a[4].w + a[5].w) + (a[6].w + a[7].w));
  acc.x += __shfl(acc.x, lane ^ 32, 64);
  acc.y += __shfl(acc.y, lane ^ 32, 64);
  acc.z += __shfl(acc.z, lane ^ 32, 64);
  acc.w += __shfl(acc.w, lane ^ 32, 64);
  if (half == 0 && hl < 24)
    *((float4*)(side + (size_t)row * DD) + hl) = acc;
}

// ========== fused bi-interaction via bf16 MFMA ==========
// block = 256 thr = 4 waves, 64 nodes; wave w -> nodes w*16..w*16+15, all 96 j.
// A-frag: lane l holds x[row=l&15][k=(l>>4)*8 + 0..7] (8 contiguous bf16).
// B-frag: Wb[j][k] row-major IS B^T: lane l holds Wb[j=t*16+(l&15)][same k].
// D: col(j-within-tile)=l&15, row(node-within-16)=(l>>4)*4+reg  [m89].
__global__ __launch_bounds__(256) void fuse4_kernel(
    const float* __restrict__ ego, const float* __restrict__ side,
    const unsigned short* __restrict__ Wb1, const unsigned short* __restrict__ Wb2,
    const float* __restrict__ b1, const float* __restrict__ b2,
    float* __restrict__ out)
{
  __shared__ unsigned short xs[FN * XST];
  __shared__ unsigned short ys[FN * XST];
  int tid = threadIdx.x;
  int nbase = blockIdx.x * FN;

  // stage x=ego+side, y=ego*side as bf16 (FN*24 float4 units, 6 iters/thread)
  for (int i = tid; i < FN * 24; i += 256) {
    int r = i / 24, c4 = i - r * 24;
    float4 e = make_float4(0.f, 0.f, 0.f, 0.f), s = e;
    if (nbase + r < NN) {
      e = ((const float4*)(ego + (size_t)(nbase + r) * DD))[c4];
      s = ((const float4*)(side + (size_t)(nbase + r) * DD))[c4];
    }
    short4v xv, yv;
    xv.x = (short)f2bf(e.x + s.x); xv.y = (short)f2bf(e.y + s.y);
    xv.z = (short)f2bf(e.z + s.z); xv.w = (short)f2bf(e.w + s.w);
    yv.x = (short)f2bf(e.x * s.x); yv.y = (short)f2bf(e.y * s.y);
    yv.z = (short)f2bf(e.z * s.z); yv.w = (short)f2bf(e.w * s.w);
    *(short4v*)(xs + r * XST + c4 * 4) = xv;
    *(short4v*)(ys + r * XST + c4 * 4) = yv;
  }
  __syncthreads();

  int w = tid >> 6, l = tid & 63;
  int lrow = l & 15, lk = l >> 4;   // lk = k-group 0..3

  f32x4 acc1[6], acc2[6];
#pragma unroll
  for (int t = 0; t < 6; ++t) {
    acc1[t] = (f32x4){0.f, 0.f, 0.f, 0.f};
    acc2[t] = (f32x4){0.f, 0.f, 0.f, 0.f};
  }

  const unsigned short* xrow = xs + (w * 16 + lrow) * XST + lk * 8;
  const unsigned short* yrow = ys + (w * 16 + lrow) * XST + lk * 8;

#pragma unroll
  for (int kk = 0; kk < 3; ++kk) {
    short8v ax = *(const short8v*)(xrow + kk * 32);
    short8v ay = *(const short8v*)(yrow + kk * 32);
    int kb = kk * 32 + lk * 8;
#pragma unroll
    for (int t = 0; t < 6; ++t) {
      int j = t * 16 + lrow;
      short8v bw1 = *(const short8v*)(Wb1 + j * DD + kb);
      short8v bw2 = *(const short8v*)(Wb2 + j * DD + kb);
      acc1[t] = __builtin_amdgcn_mfma_f32_16x16x32_bf16(ax, bw1, acc1[t], 0, 0, 0);
      acc2[t] = __builtin_amdgcn_mfma_f32_16x16x32_bf16(ay, bw2, acc2[t], 0, 0, 0);
    }
  }

  int node0 = nbase + w * 16 + lk * 4;
#pragma unroll
  for (int t = 0; t < 6; ++t) {
    int j = t * 16 + lrow;
    float bb1 = b1[j], bb2 = b2[j];
#pragma unroll
    for (int i = 0; i < 4; ++i) {
      int node = node0 + i;
      if (node < NN)
        out[(size_t)node * DD + j] = lrelu(acc1[t][i] + bb1) + lrelu(acc2[t][i] + bb2);
    }
  }
}

// ================= launch =================
extern "C" void kernel_launch(void* const* d_in, const int* in_sizes, int n_in,
                              void* d_out, int out_size, void* d_ws, size_t ws_size,
                              hipStream_t stream) {
  const float* ego   = (const float*)d_in[0];
  const float* avals = (const float*)d_in[1];
  const float* W1    = (const float*)d_in[2];
  const float* b1    = (const float*)d_in[3];
  const float* W2    = (const float*)d_in[4];
  const float* b2    = (const float*)d_in[5];
  const int* arows   = (const int*)d_in[6];
  const int* acols   = (const int*)d_in[7];
  float* out = (float*)d_out;

  size_t off = 0;
  auto bump = [&](size_t bytes) {
    size_t o = off;
    off += (bytes + 1023) & ~(size_t)1023;
    return o;
  };
  char* ws = (char*)d_ws;
  size_t o_cnt  = bump((size_t)NN * 4);
  size_t o_rs   = bump((size_t)(NN + 1) * 4);
  size_t o_wp   = bump((size_t)NN * 4);
  size_t o_bs   = bump((size_t)NB * 4);
  size_t o_be   = bump((size_t)NB * 4);
  size_t o_cv   = bump((size_t)NE * 8);
  size_t o_wb1  = bump((size_t)DD * DD * 2);
  size_t o_wb2  = bump((size_t)DD * DD * 2);
  size_t o_egob = bump((size_t)NN * DD * 2);
  size_t o_side = bump((size_t)NN * DD * 4);
  size_t need = off;

  if (ws_size >= need) {
    int*   cnt  = (int*)(ws + o_cnt);
    int*   rs   = (int*)(ws + o_rs);
    int*   wp   = (int*)(ws + o_wp);
    int*   bs   = (int*)(ws + o_bs);
    int*   be   = (int*)(ws + o_be);
    int2*  cv   = (int2*)(ws + o_cv);
    unsigned short* Wb1  = (unsigned short*)(ws + o_wb1);
    unsigned short* Wb2  = (unsigned short*)(ws + o_wb2);
    unsigned short* egob = (unsigned short*)(ws + o_egob);
    float* side = (float*)(ws + o_side);

    hipMemsetAsync(cnt, 0, (size_t)NN * 4, stream);
    prep_kernel<<<NB_CNT + NB_W + NB_E, 256, 0, stream>>>(
        arows, cnt, W1, W2, Wb1, Wb2, ego, egob);
    scan1_kernel<<<NB, 256, 0, stream>>>(cnt, bs);
    scan2_kernel<<<1, 256, 0, stream>>>(bs, be);
    scan3_kernel<<<NB, 256, 0, stream>>>(cnt, be, rs, wp);
    fill_kernel<<<NE / 256, 256, 0, stream>>>(arows, acols, avals, wp, cv);
    agg_kernel<<<(NN + 3) / 4, 256, 0, stream>>>(egob, rs, cv, side);
    fuse4_kernel<<<(NN + FN - 1) / FN, 256, 0, stream>>>(
        ego, side, Wb1, Wb2, b1, b2, out);
  } else {
    size_t side_bytes = (size_t)NN * DD * sizeof(float);
    float* side = (ws_size >= side_bytes) ? (float*)d_ws : out;
    hipMemsetAsync(side, 0, side_bytes, stream);
    long long nthreads = (long long)NE * 32;
    int blocks = (int)((nthreads + 255) / 256);
    scatter_kernel<<<blocks, 256, 0, stream>>>(ego, avals, arows, acols, side);
    fuse_fb_kernel<<<1024, 192, 0, stream>>>(ego, side, W1, b1, W2, b2, out);
  }
}